// Round 1
// 240.053 us; speedup vs baseline: 1.0322x; 1.0322x over previous
//
#include <hip/hip_runtime.h>
#include <hip/hip_bf16.h>
#include <math.h>

#define INDIM 768
#define NROWS 32768       // 8*4096
#define KSEL  38
#define NCOLS 76
#define HID   256
#define LN_EPS 1e-5f

typedef float  f32x4  __attribute__((ext_vector_type(4)));
typedef __bf16 bf16x8 __attribute__((ext_vector_type(8)));

#define MFMA16(a,b,c) __builtin_amdgcn_mfma_f32_16x16x32_bf16((a),(b),(c),0,0,0)

// ---- workspace: shared matrices pre-packed in MFMA B-fragment order ----
// frag value(lane, j) = M[n = nt*16 + (lane&15)][k = ks*32 + (lane>>4)*8 + j]
// BfP: DFT basis,  frag = kc*5 + nt   (kc 0..23, nt 0..4)   : 120 frags
// W1P: layer1 w,   frag = mlp*48 + nt*3 + ks (nt 0..15)     : 96 frags
// W2P: layer2 w,   frag = mlp*40 + nt*8 + ks (nt 0..4)      : 80 frags
// BsP: synth basis frag = nt*3 + ks  (nt 0..47)             : 144 frags
#define OFF_BFP 0
#define OFF_W1P 122880
#define OFF_W2P 221184
#define OFF_BSP 303104

__global__ void k_prep(const int* __restrict__ idxs,
                       const float* __restrict__ mu_w1, const float* __restrict__ sg_w1,
                       const float* __restrict__ mu_w2, const float* __restrict__ sg_w2,
                       __bf16* __restrict__ BfP, __bf16* __restrict__ W1P,
                       __bf16* __restrict__ W2P, __bf16* __restrict__ BsP)
{
    int tid = blockIdx.x * blockDim.x + threadIdx.x;
    int nth = gridDim.x * blockDim.x;
    const float TH = 6.28318530717958647692f / (float)INDIM;

    for (int e = tid; e < 120 * 512; e += nth) {
        int frag = e >> 9, lane = (e >> 3) & 63, j = e & 7;
        int kc = frag / 5, nt = frag % 5;
        int c = nt * 16 + (lane & 15);
        int k = kc * 32 + ((lane >> 4) << 3) + j;
        float v = 0.f;
        if (c < NCOLS) {
            int cc = (c < KSEL) ? c : c - KSEL;
            int f = idxs[cc];
            int m = (f * k) % INDIM;
            float s, co; sincosf(TH * (float)m, &s, &co);
            v = (c < KSEL) ? co : -s;
        }
        BfP[e] = (__bf16)v;
    }
    for (int e = tid; e < 96 * 512; e += nth) {
        int frag = e >> 9, lane = (e >> 3) & 63, j = e & 7;
        int mlp = frag / 48; int r = frag % 48;
        int nt = r / 3, ks = r % 3;
        int row = nt * 16 + (lane & 15);
        int k = ks * 32 + ((lane >> 4) << 3) + j;
        const float* W = mlp ? sg_w1 : mu_w1;
        W1P[e] = (__bf16)((k < NCOLS) ? W[row * NCOLS + k] : 0.f);
    }
    for (int e = tid; e < 80 * 512; e += nth) {
        int frag = e >> 9, lane = (e >> 3) & 63, j = e & 7;
        int mlp = frag / 40; int r = frag % 40;
        int nt = r / 8, ks = r % 8;
        int row = nt * 16 + (lane & 15);
        int k = ks * 32 + ((lane >> 4) << 3) + j;
        const float* W = mlp ? sg_w2 : mu_w2;
        W2P[e] = (__bf16)((row < NCOLS) ? W[row * HID + k] : 0.f);
    }
    for (int e = tid; e < 144 * 512; e += nth) {
        int frag = e >> 9, lane = (e >> 3) & 63, j = e & 7;
        int nt = frag / 3, ks = frag % 3;
        int n = nt * 16 + (lane & 15);
        int k = ks * 32 + ((lane >> 4) << 3) + j;
        float v = 0.f;
        if (k < NCOLS) {
            int cc = (k < KSEL) ? k : k - KSEL;
            int f = idxs[cc];
            int m = (f * n) % INDIM;
            float s, co; sincosf(TH * (float)m, &s, &co);
            v = ((k < KSEL) ? co : -s) * (2.0f / (float)INDIM);
        }
        BsP[e] = (__bf16)v;
    }
}

// tanh-form gelu (error vs exact ~3e-4 on gelu out -> ~5e-6 on final out)
static __device__ inline float gelu_fast(float v) {
    float u = v * (0.79788456080286535588f + 0.03567740813636141f * v * v);
    return v / (1.f + __expf(-2.f * u));
}

// cooperative async stage of two contiguous runs (one per MLP/p-half) of
// nkb KB each into LDS: unit u (1 KB) -> dst + u*1024; wave w takes u%4==w.
// global src is per-lane (base + lane*16), LDS dst is wave-uniform (HW adds
// lane*16). Zero VGPR cost, counted in vmcnt, drained by __syncthreads().
static __device__ __forceinline__ void stage_runs(
    const __bf16* __restrict__ s0, const __bf16* __restrict__ s1,
    int nkb, char* dst, int w, int lane)
{
    typedef __attribute__((address_space(1))) const unsigned int g_u32;
    typedef __attribute__((address_space(3))) unsigned int l_u32;
    for (int u = w; u < 2 * nkb; u += 4) {
        const __bf16* s = (u < nkb) ? (s0 + u * 512) : (s1 + (u - nkb) * 512);
        __builtin_amdgcn_global_load_lds((g_u32*)(s + lane * 8),
                                         (l_u32*)(dst + u * 1024), 16, 0, 0);
    }
}

// Fused kernel, PAIR-SPLIT, with all B-operand streams double-buffered
// through LDS via global_load_lds (shared by both row tiles -> half the L2
// traffic, zero-VGPR prefetch decouples L2 latency from the MFMA chain).
// LDS region R (24 KB) time-shares: ph1 SB(2x10K) -> PA(10K) -> ph2 SB(2x12K)
// -> GW(17K) -> ph3 SB(2x8K) -> PA(10K) -> ph5 SB(2x12K); every reuse is
// separated by a __syncthreads in the schedule below.
__global__ __launch_bounds__(256, 4) void k_fused(
    const float* __restrict__ x, const float* __restrict__ eps,
    const __bf16* __restrict__ Bf, const __bf16* __restrict__ W1f,
    const __bf16* __restrict__ W2f, const __bf16* __restrict__ Bs,
    const float* __restrict__ mu_b1, const float* __restrict__ mu_g,
    const float* __restrict__ mu_be, const float* __restrict__ mu_b2,
    const float* __restrict__ sg_b1, const float* __restrict__ sg_g,
    const float* __restrict__ sg_be, const float* __restrict__ sg_b2,
    float* __restrict__ out)
{
    __shared__ __align__(16) __bf16 tbuf[2][1664];   // per-tile 16x104 transpose buf
    __shared__ __align__(16) char   R[24576];        // staging / PA / GW overlay
    float*  PA = (float*)R;          // [2][1280] f32 (ph1 combine, ph4)
    __bf16* GW = (__bf16*)R;         // [4][2176] bf16 (ph2->ph3 gelu buf)

    int tid = threadIdx.x;
    int w = tid >> 6, lane = tid & 63, q = lane >> 4, l16 = lane & 15;
    int t = w >> 1, p = w & 1;
    int rbase = blockIdx.x * 32 + t * 16;

    // ---------------- Phase 1: DFT, this wave does K-half p (12 kc) ----------
    // B staged: chunk kk = frags [kc=kk]*5 (p0) + [kc=12+kk]*5 (p1) = 10 KB.
    f32x4 acc[5] = {};
    {
        const float* xrow = x + (size_t)(rbase + l16) * INDIM + p * 384 + q * 8;
        stage_runs(Bf, Bf + (size_t)60 * 512, 5, R, w, lane);          // chunk 0
        float4 f0 = ((const float4*)xrow)[0];
        float4 f1 = ((const float4*)xrow)[1];
        __syncthreads();
        #pragma unroll
        for (int kk = 0; kk < 12; ++kk) {
            int buf = kk & 1;
            float4 n0, n1;
            if (kk < 11) {
                stage_runs(Bf + (size_t)(kk + 1) * 5 * 512,
                           Bf + (size_t)(13 + kk) * 5 * 512,
                           5, R + (buf ^ 1) * 10240, w, lane);
                n0 = ((const float4*)(xrow + (kk + 1) * 32))[0];       // x prefetch
                n1 = ((const float4*)(xrow + (kk + 1) * 32))[1];
            }
            union { __bf16 h[8]; bf16x8 v; } a;
            a.h[0]=(__bf16)f0.x; a.h[1]=(__bf16)f0.y; a.h[2]=(__bf16)f0.z; a.h[3]=(__bf16)f0.w;
            a.h[4]=(__bf16)f1.x; a.h[5]=(__bf16)f1.y; a.h[6]=(__bf16)f1.z; a.h[7]=(__bf16)f1.w;
            const char* bb = R + buf * 10240 + p * 5120 + (size_t)lane * 16;
            #pragma unroll
            for (int nt = 0; nt < 5; ++nt) {
                bf16x8 b = *(const bf16x8*)(bb + nt * 1024);
                acc[nt] = MFMA16(a.v, b, acc[nt]);
            }
            __syncthreads();     // chunk kk consumed; chunk kk+1 staged+drained
            if (kk < 11) { f0 = n0; f1 = n1; }
        }
    }
    // combine halves (fp32) + transpose to A-layout in tbuf[t]
    // (post-loop barrier already passed: SB dead, PA region free)
    if (p == 1) {
        #pragma unroll
        for (int nt = 0; nt < 5; ++nt)
            #pragma unroll
            for (int r = 0; r < 4; ++r)
                PA[t * 1280 + (q * 4 + r) * 80 + nt * 16 + l16] = acc[nt][r];
    }
    __syncthreads();
    if (p == 0) {
        #pragma unroll
        for (int nt = 0; nt < 5; ++nt)
            #pragma unroll
            for (int r = 0; r < 4; ++r) {
                float v = acc[nt][r] + PA[t * 1280 + (q * 4 + r) * 80 + nt * 16 + l16];
                tbuf[t][(q * 4 + r) * 104 + nt * 16 + l16] = (__bf16)v;
            }
        #pragma unroll
        for (int r = 0; r < 4; ++r)
            tbuf[t][(q * 4 + r) * 104 + 80 + l16] = (__bf16)0.f;
    }
    __syncthreads();
    bf16x8 a1[3];
    #pragma unroll
    for (int ks = 0; ks < 3; ++ks)
        a1[ks] = *(const bf16x8*)&tbuf[t][l16 * 104 + ks * 32 + q * 8];

    // ---------------- Phase 2: this wave's MLP (mlp = p), layer1 -------------
    // B staged: chunk c = nt{2c,2c+1} x ks{0..2} for both p = 12 KB, 8 chunks.
    const float* b1 = p ? sg_b1 : mu_b1;
    const float* g  = p ? sg_g  : mu_g;
    const float* be = p ? sg_be : mu_be;

    stage_runs(W1f, W1f + (size_t)48 * 512, 6, R, w, lane);            // chunk 0
    __syncthreads();
    f32x4 h[16] = {};
    #pragma unroll
    for (int c = 0; c < 8; ++c) {
        int buf = c & 1;
        if (c < 7)
            stage_runs(W1f + (size_t)(6 * (c + 1)) * 512,
                       W1f + (size_t)(48 + 6 * (c + 1)) * 512,
                       6, R + (buf ^ 1) * 12288, w, lane);
        const char* bb = R + buf * 12288 + p * 6144 + (size_t)lane * 16;
        #pragma unroll
        for (int ntl = 0; ntl < 2; ++ntl) {
            int nt = 2 * c + ntl;
            #pragma unroll
            for (int ks = 0; ks < 3; ++ks) {
                bf16x8 b = *(const bf16x8*)(bb + (ntl * 3 + ks) * 1024);
                h[nt] = MFMA16(a1[ks], b, h[nt]);
            }
        }
        __syncthreads();
    }
    float s[4] = {}, ss[4] = {};
    #pragma unroll
    for (int nt = 0; nt < 16; ++nt) {
        float bb = b1[nt * 16 + l16];
        #pragma unroll
        for (int r = 0; r < 4; ++r) {
            float v = h[nt][r] + bb; h[nt][r] = v;
            s[r] += v; ss[r] += v * v;
        }
    }
    #pragma unroll
    for (int off = 1; off < 16; off <<= 1)
        #pragma unroll
        for (int r = 0; r < 4; ++r) {
            s[r] += __shfl_xor(s[r], off); ss[r] += __shfl_xor(ss[r], off);
        }
    float mean[4], rstd[4];
    #pragma unroll
    for (int r = 0; r < 4; ++r) {
        mean[r] = s[r] * (1.f / 256.f);
        rstd[r] = rsqrtf(ss[r] * (1.f / 256.f) - mean[r] * mean[r] + LN_EPS);
    }
    // LN + gelu -> wave-private half-buffer (stride 136), two K-halves
    // (GW overlays the ph2 staging buffers: all waves passed the last chunk
    //  barrier, SB2 is dead)
    __bf16* gw = &GW[w * 2176];
    bf16x8 a2[8];
    #pragma unroll
    for (int half = 0; half < 2; ++half) {
        #pragma unroll
        for (int ntl = 0; ntl < 8; ++ntl) {
            int nt = half * 8 + ntl;
            int i = nt * 16 + l16;
            float gv = g[i], bev = be[i];
            #pragma unroll
            for (int r = 0; r < 4; ++r)
                gw[(q * 4 + r) * 136 + ntl * 16 + l16] =
                    (__bf16)gelu_fast((h[nt][r] - mean[r]) * rstd[r] * gv + bev);
        }
        #pragma unroll
        for (int ks = 0; ks < 4; ++ks)
            a2[half * 4 + ks] = *(const bf16x8*)&gw[l16 * 136 + ks * 32 + q * 8];
    }
    __syncthreads();   // all a2 reads done -> GW region reusable for ph3 SB

    // ---------------- Phase 3: layer2 (this wave's MLP) ----------------------
    // B staged: chunk c = nt (c>>1), ks-half (c&1), both p = 8 KB, 10 chunks.
    stage_runs(W2f, W2f + (size_t)40 * 512, 4, R, w, lane);            // chunk 0
    __syncthreads();
    f32x4 o[5] = {};
    #pragma unroll
    for (int c = 0; c < 10; ++c) {
        int buf = c & 1;
        if (c < 9) {
            int nn = (c + 1) >> 1, hf = (c + 1) & 1;
            stage_runs(W2f + (size_t)(nn * 8 + hf * 4) * 512,
                       W2f + (size_t)(40 + nn * 8 + hf * 4) * 512,
                       4, R + (buf ^ 1) * 8192, w, lane);
        }
        int nt = c >> 1, hf = c & 1;
        const char* bb = R + buf * 8192 + p * 4096 + (size_t)lane * 16;
        #pragma unroll
        for (int k4 = 0; k4 < 4; ++k4) {
            bf16x8 b = *(const bf16x8*)(bb + k4 * 1024);
            o[nt] = MFMA16(a2[hf * 4 + k4], b, o[nt]);
        }
        __syncthreads();
    }

    // ---------------- Phase 4: z = (mu+b2m) + eps*(sg+b2s) -------------------
    // (last ph3 barrier passed: SB3 dead, PA region free)
    float ev[5][4];
    if (p == 0) {
        // publish o_mu
        #pragma unroll
        for (int nt = 0; nt < 5; ++nt)
            #pragma unroll
            for (int r = 0; r < 4; ++r)
                PA[t * 1280 + (q * 4 + r) * 80 + nt * 16 + l16] = o[nt][r];
    } else {
        // prefetch eps
        #pragma unroll
        for (int nt = 0; nt < 5; ++nt) {
            int j = nt * 16 + l16;
            #pragma unroll
            for (int r = 0; r < 4; ++r)
                ev[nt][r] = (j < NCOLS)
                    ? eps[(size_t)(rbase + q * 4 + r) * NCOLS + j] : 0.f;
        }
    }
    __syncthreads();
    if (p == 1) {
        #pragma unroll
        for (int nt = 0; nt < 5; ++nt) {
            int j = nt * 16 + l16;
            float b2m = (j < NCOLS) ? mu_b2[j] : 0.f;
            float b2s = (j < NCOLS) ? sg_b2[j] : 0.f;
            #pragma unroll
            for (int r = 0; r < 4; ++r) {
                float z = 0.f;
                if (j < NCOLS) {
                    float omu = PA[t * 1280 + (q * 4 + r) * 80 + j];
                    z = (omu + b2m) + ev[nt][r] * (o[nt][r] + b2s);
                }
                tbuf[t][(q * 4 + r) * 104 + j] = (__bf16)z;
            }
        }
        #pragma unroll
        for (int r = 0; r < 4; ++r)
            tbuf[t][(q * 4 + r) * 104 + 80 + l16] = (__bf16)0.f;
    }
    __syncthreads();   // z ready; PA dead -> ph5 staging may reuse R
    bf16x8 az[3];
    #pragma unroll
    for (int ks = 0; ks < 3; ++ks)
        az[ks] = *(const bf16x8*)&tbuf[t][l16 * 104 + ks * 32 + q * 8];
    stage_runs(Bs, Bs + (size_t)72 * 512, 6, R, w, lane);              // chunk 0
    __syncthreads();

    // ---------------- Phase 5: synthesis, this wave does 24 n-tiles ----------
    // B staged: chunk c = 2 n-tiles x ks{0..2} for both p = 12 KB, 12 chunks.
    #pragma unroll
    for (int c = 0; c < 12; ++c) {
        int buf = c & 1;
        if (c < 11)
            stage_runs(Bs + (size_t)(6 * (c + 1)) * 512,
                       Bs + (size_t)(72 + 6 * (c + 1)) * 512,
                       6, R + (buf ^ 1) * 12288, w, lane);
        const char* bb = R + buf * 12288 + p * 6144 + (size_t)lane * 16;
        #pragma unroll
        for (int kloc = 0; kloc < 2; ++kloc) {
            int nt = p * 24 + 2 * c + kloc;
            f32x4 oc = {};
            #pragma unroll
            for (int ks = 0; ks < 3; ++ks) {
                bf16x8 b = *(const bf16x8*)(bb + (kloc * 3 + ks) * 1024);
                oc = MFMA16(az[ks], b, oc);
            }
            #pragma unroll
            for (int r = 0; r < 4; ++r)
                out[(size_t)(rbase + q * 4 + r) * INDIM + nt * 16 + l16] = oc[r];
        }
        if (c < 11) __syncthreads();
    }
}

extern "C" void kernel_launch(void* const* d_in, const int* in_sizes, int n_in,
                              void* d_out, int out_size, void* d_ws, size_t ws_size,
                              hipStream_t stream)
{
    const float* x     = (const float*)d_in[0];
    const float* eps   = (const float*)d_in[1];
    const int*   idxs  = (const int*)  d_in[2];
    const float* mu_w1 = (const float*)d_in[3];
    const float* mu_b1 = (const float*)d_in[4];
    const float* mu_g  = (const float*)d_in[5];
    const float* mu_be = (const float*)d_in[6];
    const float* mu_w2 = (const float*)d_in[7];
    const float* mu_b2 = (const float*)d_in[8];
    const float* sg_w1 = (const float*)d_in[9];
    const float* sg_b1 = (const float*)d_in[10];
    const float* sg_g  = (const float*)d_in[11];
    const float* sg_be = (const float*)d_in[12];
    const float* sg_w2 = (const float*)d_in[13];
    const float* sg_b2 = (const float*)d_in[14];
    float* out = (float*)d_out;

    char* ws = (char*)d_ws;
    __bf16* BfP = (__bf16*)(ws + OFF_BFP);
    __bf16* W1P = (__bf16*)(ws + OFF_W1P);
    __bf16* W2P = (__bf16*)(ws + OFF_W2P);
    __bf16* BsP = (__bf16*)(ws + OFF_BSP);

    hipLaunchKernelGGL(k_prep, dim3(1024), dim3(256), 0, stream,
                       idxs, mu_w1, sg_w1, mu_w2, sg_w2, BfP, W1P, W2P, BsP);
    hipLaunchKernelGGL(k_fused, dim3(NROWS / 32), dim3(256), 0, stream,
                       x, eps, BfP, W1P, W2P, BsP,
                       mu_b1, mu_g, mu_be, mu_b2,
                       sg_b1, sg_g, sg_be, sg_b2, out);
}

// Round 2
// 235.730 us; speedup vs baseline: 1.0511x; 1.0183x over previous
//
#include <hip/hip_runtime.h>
#include <hip/hip_bf16.h>
#include <math.h>

#define INDIM 768
#define NROWS 32768       // 8*4096
#define KSEL  38
#define NCOLS 76
#define HID   256
#define LN_EPS 1e-5f

typedef float  f32x4  __attribute__((ext_vector_type(4)));
typedef __bf16 bf16x8 __attribute__((ext_vector_type(8)));

#define MFMA16(a,b,c) __builtin_amdgcn_mfma_f32_16x16x32_bf16((a),(b),(c),0,0,0)

// ---- workspace: shared matrices pre-packed in MFMA B-fragment order ----
// frag value(lane, j) = M[n = nt*16 + (lane&15)][k = ks*32 + (lane>>4)*8 + j]
// BfP: DFT basis,  frag = kc*5 + nt   (kc 0..23, nt 0..4)   : 120 frags
// W1P: layer1 w,   frag = mlp*48 + nt*3 + ks (nt 0..15)     : 96 frags
// W2P: layer2 w,   frag = mlp*40 + nt*8 + ks (nt 0..4)      : 80 frags
// BsP: synth basis frag = nt*3 + ks  (nt 0..47)             : 144 frags
#define OFF_BFP 0
#define OFF_W1P 122880
#define OFF_W2P 221184
#define OFF_BSP 303104

__global__ void k_prep(const int* __restrict__ idxs,
                       const float* __restrict__ mu_w1, const float* __restrict__ sg_w1,
                       const float* __restrict__ mu_w2, const float* __restrict__ sg_w2,
                       __bf16* __restrict__ BfP, __bf16* __restrict__ W1P,
                       __bf16* __restrict__ W2P, __bf16* __restrict__ BsP)
{
    int tid = blockIdx.x * blockDim.x + threadIdx.x;
    int nth = gridDim.x * blockDim.x;
    const float TH = 6.28318530717958647692f / (float)INDIM;

    for (int e = tid; e < 120 * 512; e += nth) {
        int frag = e >> 9, lane = (e >> 3) & 63, j = e & 7;
        int kc = frag / 5, nt = frag % 5;
        int c = nt * 16 + (lane & 15);
        int k = kc * 32 + ((lane >> 4) << 3) + j;
        float v = 0.f;
        if (c < NCOLS) {
            int cc = (c < KSEL) ? c : c - KSEL;
            int f = idxs[cc];
            int m = (f * k) % INDIM;
            float s, co; sincosf(TH * (float)m, &s, &co);
            v = (c < KSEL) ? co : -s;
        }
        BfP[e] = (__bf16)v;
    }
    for (int e = tid; e < 96 * 512; e += nth) {
        int frag = e >> 9, lane = (e >> 3) & 63, j = e & 7;
        int mlp = frag / 48; int r = frag % 48;
        int nt = r / 3, ks = r % 3;
        int row = nt * 16 + (lane & 15);
        int k = ks * 32 + ((lane >> 4) << 3) + j;
        const float* W = mlp ? sg_w1 : mu_w1;
        W1P[e] = (__bf16)((k < NCOLS) ? W[row * NCOLS + k] : 0.f);
    }
    for (int e = tid; e < 80 * 512; e += nth) {
        int frag = e >> 9, lane = (e >> 3) & 63, j = e & 7;
        int mlp = frag / 40; int r = frag % 40;
        int nt = r / 8, ks = r % 8;
        int row = nt * 16 + (lane & 15);
        int k = ks * 32 + ((lane >> 4) << 3) + j;
        const float* W = mlp ? sg_w2 : mu_w2;
        W2P[e] = (__bf16)((row < NCOLS) ? W[row * HID + k] : 0.f);
    }
    for (int e = tid; e < 144 * 512; e += nth) {
        int frag = e >> 9, lane = (e >> 3) & 63, j = e & 7;
        int nt = frag / 3, ks = frag % 3;
        int n = nt * 16 + (lane & 15);
        int k = ks * 32 + ((lane >> 4) << 3) + j;
        float v = 0.f;
        if (k < NCOLS) {
            int cc = (k < KSEL) ? k : k - KSEL;
            int f = idxs[cc];
            int m = (f * n) % INDIM;
            float s, co; sincosf(TH * (float)m, &s, &co);
            v = ((k < KSEL) ? co : -s) * (2.0f / (float)INDIM);
        }
        BsP[e] = (__bf16)v;
    }
}

// tanh-form gelu (error vs exact ~3e-4 on gelu out -> ~5e-6 on final out)
static __device__ inline float gelu_fast(float v) {
    float u = v * (0.79788456080286535588f + 0.03567740813636141f * v * v);
    return v / (1.f + __expf(-2.f * u));
}

// cooperative async stage: nunits x 1KB units, unit u -> dst + u*1024,
// 16 waves round-robin (u % 16 == w). Global src per-lane (base + lane*16B),
// LDS dst wave-uniform (HW adds lane*16). Zero VGPR, drained by syncthreads.
static __device__ __forceinline__ void stage16(
    const __bf16* __restrict__ src, int nunits, char* dst, int w, int lane)
{
    typedef __attribute__((address_space(1))) const unsigned int g_u32;
    typedef __attribute__((address_space(3))) unsigned int l_u32;
    for (int u = w; u < nunits; u += 16)
        __builtin_amdgcn_global_load_lds((g_u32*)(src + (size_t)u * 512 + lane * 8),
                                         (l_u32*)(dst + u * 1024), 16, 0, 0);
}

// PERSISTENT-TILE fused kernel: 1024 threads = 16 waves = 8 wave-pairs,
// 128 rows/block (8 tiles x 16), grid 256 = 1 block/CU.
// Each phase's FULL B-matrix is staged once into a 120 KB LDS region R
// (Bf 120K -> W1P 96K -> W2P 80K -> Bs 72K x2), shared by all 8 tiles:
// phase inner loops are completely barrier-free; only 14 barriers/block
// vs ~50 per 32 rows in the chunked design (per-row drain cost ~14x less).
// R overlays (all barrier-separated): PA f32[8][1280] (ph1/ph4 combine,
// 40 KB) and GW bf16 per-wave gelu buf (16*4352 = 69.6 KB).
// LDS total = 120K + tbuf 26K = 146 KB -> 1 block/CU, 4 waves/SIMD.
__global__ __launch_bounds__(1024, 4) void k_fused(
    const float* __restrict__ x, const float* __restrict__ eps,
    const __bf16* __restrict__ Bf, const __bf16* __restrict__ W1f,
    const __bf16* __restrict__ W2f, const __bf16* __restrict__ Bs,
    const float* __restrict__ mu_b1, const float* __restrict__ mu_g,
    const float* __restrict__ mu_be, const float* __restrict__ mu_b2,
    const float* __restrict__ sg_b1, const float* __restrict__ sg_g,
    const float* __restrict__ sg_be, const float* __restrict__ sg_b2,
    float* __restrict__ out)
{
    __shared__ __align__(16) char   R[122880];       // B region / PA / GW overlay
    __shared__ __align__(16) __bf16 tbuf[8][1664];   // per-tile 16x104 transpose buf
    float* PA = (float*)R;                           // [8][1280] f32

    int tid = threadIdx.x;
    int w = tid >> 6, lane = tid & 63, q = lane >> 4, l16 = lane & 15;
    int t = w >> 1, p = w & 1;
    int rbase = blockIdx.x * 128 + t * 16;

    // ---------------- Phase 1: DFT, this wave does K-half p (12 kc) ----------
    f32x4 acc[5] = {};
    {
        const float* xrow = x + (size_t)(rbase + l16) * INDIM + p * 384 + q * 8;
        stage16(Bf, 120, R, w, lane);                 // full DFT basis -> LDS
        float4 f0 = ((const float4*)xrow)[0];
        float4 f1 = ((const float4*)xrow)[1];
        __syncthreads();                              // B1: Bf ready
        #pragma unroll
        for (int kk = 0; kk < 12; ++kk) {
            float4 n0, n1;
            if (kk < 11) {                            // x prefetch, no barrier in loop
                n0 = ((const float4*)(xrow + (kk + 1) * 32))[0];
                n1 = ((const float4*)(xrow + (kk + 1) * 32))[1];
            }
            union { __bf16 h[8]; bf16x8 v; } a;
            a.h[0]=(__bf16)f0.x; a.h[1]=(__bf16)f0.y; a.h[2]=(__bf16)f0.z; a.h[3]=(__bf16)f0.w;
            a.h[4]=(__bf16)f1.x; a.h[5]=(__bf16)f1.y; a.h[6]=(__bf16)f1.z; a.h[7]=(__bf16)f1.w;
            const char* bb = R + (size_t)((p * 12 + kk) * 5) * 1024 + (size_t)lane * 16;
            #pragma unroll
            for (int nt = 0; nt < 5; ++nt) {
                bf16x8 b = *(const bf16x8*)(bb + nt * 1024);
                acc[nt] = MFMA16(a.v, b, acc[nt]);
            }
            if (kk < 11) { f0 = n0; f1 = n1; }
        }
    }
    __syncthreads();                                  // B2: Bf dead -> R reusable
    // combine halves (fp32) + transpose to A-layout in tbuf[t]
    if (p == 1) {
        #pragma unroll
        for (int nt = 0; nt < 5; ++nt)
            #pragma unroll
            for (int r = 0; r < 4; ++r)
                PA[t * 1280 + (q * 4 + r) * 80 + nt * 16 + l16] = acc[nt][r];
    }
    __syncthreads();                                  // B3: PA ready
    if (p == 0) {
        #pragma unroll
        for (int nt = 0; nt < 5; ++nt)
            #pragma unroll
            for (int r = 0; r < 4; ++r) {
                float v = acc[nt][r] + PA[t * 1280 + (q * 4 + r) * 80 + nt * 16 + l16];
                tbuf[t][(q * 4 + r) * 104 + nt * 16 + l16] = (__bf16)v;
            }
        #pragma unroll
        for (int r = 0; r < 4; ++r)
            tbuf[t][(q * 4 + r) * 104 + 80 + l16] = (__bf16)0.f;
    }
    __syncthreads();                                  // B4: tbuf ready, PA dead
    bf16x8 a1[3];
    #pragma unroll
    for (int ks = 0; ks < 3; ++ks)
        a1[ks] = *(const bf16x8*)&tbuf[t][l16 * 104 + ks * 32 + q * 8];
    stage16(W1f, 96, R, w, lane);                     // full layer-1 weights -> LDS
    __syncthreads();                                  // B5: W1P ready

    // ---------------- Phase 2: this wave's MLP (mlp = p), layer1 -------------
    const float* b1 = p ? sg_b1 : mu_b1;
    const float* g  = p ? sg_g  : mu_g;
    const float* be = p ? sg_be : mu_be;

    f32x4 h[16] = {};
    #pragma unroll
    for (int nt = 0; nt < 16; ++nt)
        #pragma unroll
        for (int ks = 0; ks < 3; ++ks) {
            bf16x8 b = *(const bf16x8*)(R + (size_t)((p * 48 + nt * 3 + ks) * 1024)
                                          + (size_t)lane * 16);
            h[nt] = MFMA16(a1[ks], b, h[nt]);
        }
    float s[4] = {}, ss[4] = {};
    #pragma unroll
    for (int nt = 0; nt < 16; ++nt) {
        float bb = b1[nt * 16 + l16];
        #pragma unroll
        for (int r = 0; r < 4; ++r) {
            float v = h[nt][r] + bb; h[nt][r] = v;
            s[r] += v; ss[r] += v * v;
        }
    }
    #pragma unroll
    for (int off = 1; off < 16; off <<= 1)
        #pragma unroll
        for (int r = 0; r < 4; ++r) {
            s[r] += __shfl_xor(s[r], off); ss[r] += __shfl_xor(ss[r], off);
        }
    float mean[4], rstd[4];
    #pragma unroll
    for (int r = 0; r < 4; ++r) {
        mean[r] = s[r] * (1.f / 256.f);
        rstd[r] = rsqrtf(ss[r] * (1.f / 256.f) - mean[r] * mean[r] + LN_EPS);
    }
    __syncthreads();                                  // B6: W1P dead -> GW overlay ok
    // LN + gelu -> wave-private buffer (stride 136), two K-halves
    __bf16* gw = (__bf16*)R + w * 2176;
    bf16x8 a2[8];
    #pragma unroll
    for (int half = 0; half < 2; ++half) {
        #pragma unroll
        for (int ntl = 0; ntl < 8; ++ntl) {
            int nt = half * 8 + ntl;
            int i = nt * 16 + l16;
            float gv = g[i], bev = be[i];
            #pragma unroll
            for (int r = 0; r < 4; ++r)
                gw[(q * 4 + r) * 136 + ntl * 16 + l16] =
                    (__bf16)gelu_fast((h[nt][r] - mean[r]) * rstd[r] * gv + bev);
        }
        #pragma unroll
        for (int ks = 0; ks < 4; ++ks)
            a2[half * 4 + ks] = *(const bf16x8*)&gw[l16 * 136 + ks * 32 + q * 8];
    }
    __syncthreads();                                  // B7: GW dead
    stage16(W2f, 80, R, w, lane);                     // full layer-2 weights -> LDS
    __syncthreads();                                  // B8: W2P ready

    // ---------------- Phase 3: layer2 (this wave's MLP) ----------------------
    f32x4 o[5] = {};
    #pragma unroll
    for (int nt = 0; nt < 5; ++nt)
        #pragma unroll
        for (int ks = 0; ks < 8; ++ks) {
            bf16x8 b = *(const bf16x8*)(R + (size_t)((p * 40 + nt * 8 + ks) * 1024)
                                          + (size_t)lane * 16);
            o[nt] = MFMA16(a2[ks], b, o[nt]);
        }
    __syncthreads();                                  // B9: W2P dead -> PA overlay ok

    // ---------------- Phase 4: z = (mu+b2m) + eps*(sg+b2s) -------------------
    float ev[5][4];
    if (p == 0) {
        // publish o_mu
        #pragma unroll
        for (int nt = 0; nt < 5; ++nt)
            #pragma unroll
            for (int r = 0; r < 4; ++r)
                PA[t * 1280 + (q * 4 + r) * 80 + nt * 16 + l16] = o[nt][r];
    } else {
        // prefetch eps
        #pragma unroll
        for (int nt = 0; nt < 5; ++nt) {
            int j = nt * 16 + l16;
            #pragma unroll
            for (int r = 0; r < 4; ++r)
                ev[nt][r] = (j < NCOLS)
                    ? eps[(size_t)(rbase + q * 4 + r) * NCOLS + j] : 0.f;
        }
    }
    __syncthreads();                                  // B10: PA(mu) ready
    if (p == 1) {
        #pragma unroll
        for (int nt = 0; nt < 5; ++nt) {
            int j = nt * 16 + l16;
            float b2m = (j < NCOLS) ? mu_b2[j] : 0.f;
            float b2s = (j < NCOLS) ? sg_b2[j] : 0.f;
            #pragma unroll
            for (int r = 0; r < 4; ++r) {
                float z = 0.f;
                if (j < NCOLS) {
                    float omu = PA[t * 1280 + (q * 4 + r) * 80 + j];
                    z = (omu + b2m) + ev[nt][r] * (o[nt][r] + b2s);
                }
                tbuf[t][(q * 4 + r) * 104 + j] = (__bf16)z;
            }
        }
        #pragma unroll
        for (int r = 0; r < 4; ++r)
            tbuf[t][(q * 4 + r) * 104 + 80 + l16] = (__bf16)0.f;
    }
    __syncthreads();                                  // B11: z ready, PA dead
    bf16x8 az[3];
    #pragma unroll
    for (int ks = 0; ks < 3; ++ks)
        az[ks] = *(const bf16x8*)&tbuf[t][l16 * 104 + ks * 32 + q * 8];
    stage16(Bs, 72, R, w, lane);                      // synth basis half 0 -> LDS
    __syncthreads();                                  // B12: half 0 ready

    // ---------------- Phase 5: synthesis, 2 halves x 12 n-tiles/wave ---------
    #pragma unroll
    for (int half = 0; half < 2; ++half) {
        if (half == 1) {
            __syncthreads();                          // B13: half 0 dead
            stage16(Bs + (size_t)72 * 512, 72, R, w, lane);
            __syncthreads();                          // B14: half 1 ready
        }
        #pragma unroll 4
        for (int c = 0; c < 12; ++c) {
            int ntl = p * 12 + c;                     // frag-local n-tile in half
            int nt  = half * 24 + ntl;                // global n-tile
            f32x4 oc = {};
            #pragma unroll
            for (int ks = 0; ks < 3; ++ks) {
                bf16x8 b = *(const bf16x8*)(R + (size_t)((ntl * 3 + ks) * 1024)
                                              + (size_t)lane * 16);
                oc = MFMA16(az[ks], b, oc);
            }
            #pragma unroll
            for (int r = 0; r < 4; ++r)
                out[(size_t)(rbase + q * 4 + r) * INDIM + nt * 16 + l16] = oc[r];
        }
    }
}

extern "C" void kernel_launch(void* const* d_in, const int* in_sizes, int n_in,
                              void* d_out, int out_size, void* d_ws, size_t ws_size,
                              hipStream_t stream)
{
    const float* x     = (const float*)d_in[0];
    const float* eps   = (const float*)d_in[1];
    const int*   idxs  = (const int*)  d_in[2];
    const float* mu_w1 = (const float*)d_in[3];
    const float* mu_b1 = (const float*)d_in[4];
    const float* mu_g  = (const float*)d_in[5];
    const float* mu_be = (const float*)d_in[6];
    const float* mu_w2 = (const float*)d_in[7];
    const float* mu_b2 = (const float*)d_in[8];
    const float* sg_w1 = (const float*)d_in[9];
    const float* sg_b1 = (const float*)d_in[10];
    const float* sg_g  = (const float*)d_in[11];
    const float* sg_be = (const float*)d_in[12];
    const float* sg_w2 = (const float*)d_in[13];
    const float* sg_b2 = (const float*)d_in[14];
    float* out = (float*)d_out;

    char* ws = (char*)d_ws;
    __bf16* BfP = (__bf16*)(ws + OFF_BFP);
    __bf16* W1P = (__bf16*)(ws + OFF_W1P);
    __bf16* W2P = (__bf16*)(ws + OFF_W2P);
    __bf16* BsP = (__bf16*)(ws + OFF_BSP);

    hipLaunchKernelGGL(k_prep, dim3(1024), dim3(256), 0, stream,
                       idxs, mu_w1, sg_w1, mu_w2, sg_w2, BfP, W1P, W2P, BsP);
    hipLaunchKernelGGL(k_fused, dim3(NROWS / 128), dim3(1024), 0, stream,
                       x, eps, BfP, W1P, W2P, BsP,
                       mu_b1, mu_g, mu_be, mu_b2,
                       sg_b1, sg_g, sg_be, sg_b2, out);
}